// Round 2
// baseline (1130.392 us; speedup 1.0000x reference)
//
#include <hip/hip_runtime.h>
#include <hip/hip_bf16.h>

// Fully-fused MLP: featurize + (GEMM+LN+tanh) x3 + final dot, one kernel,
// 64 rows/block, all intermediates in LDS. Workspace: bf16 weights only
// (4.33 MB) -- robust to small ws_size (Round-1 crash suspect: ws overflow).

typedef __attribute__((ext_vector_type(8))) short bf16x8;   // 8 bf16 = 4 VGPRs
typedef __attribute__((ext_vector_type(4))) float f32x4;    // MFMA accumulator

#define LN_EPS 1e-5f

__device__ __forceinline__ float bf2f(short u) {
  union { unsigned u; float f; } c;
  c.u = ((unsigned)(unsigned short)u) << 16;
  return c.f;
}
// RNE float->bf16
__device__ __forceinline__ unsigned short f2bf(float f) {
  union { float f; unsigned u; } c; c.f = f;
  unsigned u = c.u;
  u += 0x7FFFu + ((u >> 16) & 1u);
  return (unsigned short)(u >> 16);
}

// ---------------------------------------------------------------- convert
__global__ void convert_f2bf(const float* __restrict__ src,
                             unsigned short* __restrict__ dst, int n4) {
  int i = blockIdx.x * blockDim.x + threadIdx.x;
  if (i >= n4) return;
  float4 v = reinterpret_cast<const float4*>(src)[i];
  ushort4 o;
  o.x = f2bf(v.x); o.y = f2bf(v.y); o.z = f2bf(v.z); o.w = f2bf(v.w);
  reinterpret_cast<ushort4*>(dst)[i] = o;
}

// ---------------------------------------------------------------- GEMM phase
// acc[mt][nt] += A(LDS) @ W^T(global). MFMA 16x16x32 bf16.
// A-frag: m=lane&15, k=quad*8+j. B-frag: n=lane&15 (W row), k=quad*8+j.
// D: col=lane&15 (n), row=quad*4+reg (m).
template <int NSTEPS, int NT, int ASTRIDE>
__device__ __forceinline__ void gemm_phase(
    f32x4 (&acc)[4][NT], const unsigned short* h_s,
    const unsigned short* __restrict__ Wb, int K, int wavecol0,
    int quad, int l15) {
  const int kb0 = quad * 8;
  const unsigned short* wp[NT];
#pragma unroll
  for (int nt = 0; nt < NT; ++nt)
    wp[nt] = Wb + (long)(wavecol0 + nt * 16 + l15) * K + kb0;
  bf16x8 bcur[NT];
#pragma unroll
  for (int nt = 0; nt < NT; ++nt)
    bcur[nt] = *reinterpret_cast<const bf16x8*>(wp[nt]);
#pragma unroll 2
  for (int kc = 0; kc < NSTEPS; ++kc) {
    bf16x8 bnxt[NT];
    if (kc + 1 < NSTEPS) {
#pragma unroll
      for (int nt = 0; nt < NT; ++nt)
        bnxt[nt] = *reinterpret_cast<const bf16x8*>(wp[nt] + (kc + 1) * 32);
    }
    bf16x8 a[4];
#pragma unroll
    for (int mt = 0; mt < 4; ++mt)
      a[mt] = *reinterpret_cast<const bf16x8*>(
          h_s + (mt * 16 + l15) * ASTRIDE + kc * 32 + kb0);
#pragma unroll
    for (int mt = 0; mt < 4; ++mt)
#pragma unroll
      for (int nt = 0; nt < NT; ++nt)
        acc[mt][nt] = __builtin_amdgcn_mfma_f32_16x16x32_bf16(
            a[mt], bcur[nt], acc[mt][nt], 0, 0, 0);
#pragma unroll
    for (int nt = 0; nt < NT; ++nt) bcur[nt] = bnxt[nt];
  }
}

// --------------------------------------------------- LN+tanh epilogue (L0/L1)
// Row stats across the whole block (each wave holds 128 of N cols for all 64
// rows), then act = tanh((v-m)*r*g+be) written back to h_s (stride 1032).
template <int NT>
__device__ __forceinline__ void ln_tanh_epilogue(
    f32x4 (&acc)[4][NT], unsigned short* h_s,
    const float* __restrict__ bias, const float* __restrict__ g,
    const float* __restrict__ be, float* rsum_s, float* rsq_s, float2* mr_s,
    float invN, int wavecol0, int quad, int l15, int t) {
  float bv[NT], gv[NT], bev[NT];
#pragma unroll
  for (int nt = 0; nt < NT; ++nt) {
    const int c = wavecol0 + nt * 16 + l15;
    bv[nt] = bias[c]; gv[nt] = g[c]; bev[nt] = be[c];
  }
#pragma unroll
  for (int mt = 0; mt < 4; ++mt) {
#pragma unroll
    for (int reg = 0; reg < 4; ++reg) {
      float s = 0.f, ss = 0.f;
#pragma unroll
      for (int nt = 0; nt < NT; ++nt) {
        float v = acc[mt][nt][reg] + bv[nt];
        s += v; ss += v * v;
      }
#pragma unroll
      for (int m = 8; m >= 1; m >>= 1) {
        s += __shfl_xor(s, m, 16);
        ss += __shfl_xor(ss, m, 16);
      }
      if (l15 == 0) {
        atomicAdd(&rsum_s[mt * 16 + quad * 4 + reg], s);
        atomicAdd(&rsq_s[mt * 16 + quad * 4 + reg], ss);
      }
    }
  }
  __syncthreads();
  if (t < 64) {
    float mean = rsum_s[t] * invN;
    float var = rsq_s[t] * invN - mean * mean;
    mr_s[t] = make_float2(mean, 1.0f / sqrtf(var + LN_EPS));
    rsum_s[t] = 0.f; rsq_s[t] = 0.f;   // ready for next layer
  }
  __syncthreads();
#pragma unroll
  for (int mt = 0; mt < 4; ++mt)
#pragma unroll
    for (int reg = 0; reg < 4; ++reg) {
      const int row = mt * 16 + quad * 4 + reg;
      const float2 mr = mr_s[row];
#pragma unroll
      for (int nt = 0; nt < NT; ++nt) {
        float v = acc[mt][nt][reg] + bv[nt];
        float a = tanhf((v - mr.x) * mr.y * gv[nt] + bev[nt]);
        h_s[row * 1032 + wavecol0 + nt * 16 + l15] = f2bf(a);
      }
    }
  __syncthreads();
}

// ---------------------------------------------------------------- fused MLP
__global__ __launch_bounds__(512, 2) void fused_mlp(
    const float* __restrict__ x,
    const float* __restrict__ kc_emb, const float* __restrict__ nl_emb,
    const float* __restrict__ op_w, const float* __restrict__ op_b,
    const float* __restrict__ ic_emb, const float* __restrict__ is_emb,
    const float* __restrict__ ii_emb,
    const unsigned short* __restrict__ W0b, const float* __restrict__ b0,
    const float* __restrict__ g0, const float* __restrict__ be0,
    const unsigned short* __restrict__ W1b, const float* __restrict__ b1,
    const float* __restrict__ g1, const float* __restrict__ be1,
    const unsigned short* __restrict__ W2b, const float* __restrict__ b2,
    const float* __restrict__ g2, const float* __restrict__ be2,
    const float* __restrict__ W3, const float* __restrict__ b3,
    float* __restrict__ out) {
  // One buffer, three lives: F (stride 584, 64x576), h1, h2 (stride 1032,
  // 64x1024). Phases never coexist (h written only after all reads of the
  // previous occupant are barrier-complete).
  __shared__ __align__(16) unsigned short h_s[64 * 1032];  // 132,096 B
  __shared__ float rsum_s[64], rsq_s[64], out_s[64];
  __shared__ float2 mr_s[64];

  const int t = threadIdx.x;
  const int wave = t >> 6, lane = t & 63, quad = lane >> 4, l15 = lane & 15;
  const long rowbase = (long)blockIdx.x * 64;

  if (t < 64) { rsum_s[t] = 0.f; rsq_s[t] = 0.f; out_s[t] = 0.f; }

  // ---- featurize: 64 rows -> h_s, stride 584 (pad cols 576..583 unused)
#pragma unroll
  for (int rr = 0; rr < 8; ++rr) {
    const int r = rr * 8 + wave;
    const float* xr = x + (rowbase + r) * 323;
    unsigned short* fr = h_s + r * 584;
#pragma unroll
    for (int i = 0; i < 9; ++i) {
      const int f = lane + i * 64;
      float v;
      if (f < 32) {
        v = kc_emb[(int)xr[0] * 32 + f];
      } else if (f < 64) {
        v = nl_emb[(int)xr[1] * 32 + (f - 32)];
      } else if (f < 176) {
        const int j = (f - 64) >> 1, c = (f - 64) & 1;
        v = xr[2 + j] * op_w[j * 2 + c] + op_b[j * 2 + c];
      } else if (f < 178) {
        v = xr[58 + (f - 176)];
      } else if (f < 568) {
        const int gidx = f - 178;
        const int blk = gidx / 26;
        const int r2 = gidx - blk * 26;
        const int base = 60 + 17 * blk;
        if (r2 < 14)      v = xr[base + r2];
        else if (r2 < 18) v = ic_emb[(int)xr[base + 14] * 4 + (r2 - 14)];
        else if (r2 < 22) v = is_emb[(int)xr[base + 15] * 4 + (r2 - 18)];
        else              v = ii_emb[(int)xr[base + 16] * 4 + (r2 - 22)];
      } else {
        v = xr[315 + (f - 568)];
      }
      fr[f] = f2bf(v);
    }
  }
  __syncthreads();

  const f32x4 fz = {0.f, 0.f, 0.f, 0.f};

  // ---- layer 0: K=576 (18 k-steps), N=1024, wave cols = wave*128..+127
  {
    f32x4 acc[4][8];
#pragma unroll
    for (int mt = 0; mt < 4; ++mt)
#pragma unroll
      for (int nt = 0; nt < 8; ++nt) acc[mt][nt] = fz;
    gemm_phase<18, 8, 584>(acc, h_s, W0b, 576, wave * 128, quad, l15);
    ln_tanh_epilogue<8>(acc, h_s, b0, g0, be0, rsum_s, rsq_s, mr_s,
                        1.0f / 1024.f, wave * 128, quad, l15, t);
  }
  // ---- layer 1: K=1024 (32 k-steps), N=1024
  {
    f32x4 acc[4][8];
#pragma unroll
    for (int mt = 0; mt < 4; ++mt)
#pragma unroll
      for (int nt = 0; nt < 8; ++nt) acc[mt][nt] = fz;
    gemm_phase<32, 8, 1032>(acc, h_s, W1b, 1024, wave * 128, quad, l15);
    ln_tanh_epilogue<8>(acc, h_s, b1, g1, be1, rsum_s, rsq_s, mr_s,
                        1.0f / 1024.f, wave * 128, quad, l15, t);
  }
  // ---- layer 2 + final dot: K=1024, N=512, wave cols = wave*64..+63
  {
    f32x4 acc[4][4];
#pragma unroll
    for (int mt = 0; mt < 4; ++mt)
#pragma unroll
      for (int nt = 0; nt < 4; ++nt) acc[mt][nt] = fz;
    gemm_phase<32, 4, 1032>(acc, h_s, W2b, 1024, wave * 64, quad, l15);

    float bv[4], gv[4], bev[4], wv[4];
#pragma unroll
    for (int nt = 0; nt < 4; ++nt) {
      const int c = wave * 64 + nt * 16 + l15;
      bv[nt] = b2[c]; gv[nt] = g2[c]; bev[nt] = be2[c]; wv[nt] = W3[c];
    }
#pragma unroll
    for (int mt = 0; mt < 4; ++mt) {
#pragma unroll
      for (int reg = 0; reg < 4; ++reg) {
        float s = 0.f, ss = 0.f;
#pragma unroll
        for (int nt = 0; nt < 4; ++nt) {
          float v = acc[mt][nt][reg] + bv[nt];
          s += v; ss += v * v;
        }
#pragma unroll
        for (int m = 8; m >= 1; m >>= 1) {
          s += __shfl_xor(s, m, 16);
          ss += __shfl_xor(ss, m, 16);
        }
        if (l15 == 0) {
          atomicAdd(&rsum_s[mt * 16 + quad * 4 + reg], s);
          atomicAdd(&rsq_s[mt * 16 + quad * 4 + reg], ss);
        }
      }
    }
    __syncthreads();
    if (t < 64) {
      float mean = rsum_s[t] * (1.0f / 512.f);
      float var = rsq_s[t] * (1.0f / 512.f) - mean * mean;
      mr_s[t] = make_float2(mean, 1.0f / sqrtf(var + LN_EPS));
    }
    __syncthreads();
#pragma unroll
    for (int mt = 0; mt < 4; ++mt) {
#pragma unroll
      for (int reg = 0; reg < 4; ++reg) {
        const int row = mt * 16 + quad * 4 + reg;
        const float2 mr = mr_s[row];
        float o = 0.f;
#pragma unroll
        for (int nt = 0; nt < 4; ++nt) {
          float v = acc[mt][nt][reg] + bv[nt];
          float a = tanhf((v - mr.x) * mr.y * gv[nt] + bev[nt]);
          o += a * wv[nt];
        }
#pragma unroll
        for (int m = 8; m >= 1; m >>= 1) o += __shfl_xor(o, m, 16);
        if (l15 == 0) atomicAdd(&out_s[row], o);
      }
    }
    __syncthreads();
    if (t < 64) out[rowbase + t] = out_s[t] + b3[0];
  }
}

// ---------------------------------------------------------------- launch
extern "C" void kernel_launch(void* const* d_in, const int* in_sizes, int n_in,
                              void* d_out, int out_size, void* d_ws,
                              size_t ws_size, hipStream_t stream) {
  const float* x      = (const float*)d_in[0];
  const float* kc_emb = (const float*)d_in[1];
  const float* nl_emb = (const float*)d_in[2];
  const float* op_w   = (const float*)d_in[3];
  const float* op_b   = (const float*)d_in[4];
  const float* ic_emb = (const float*)d_in[5];
  const float* is_emb = (const float*)d_in[6];
  const float* ii_emb = (const float*)d_in[7];
  const float* W0  = (const float*)d_in[8];
  const float* b0  = (const float*)d_in[9];
  const float* W1  = (const float*)d_in[10];
  const float* b1  = (const float*)d_in[11];
  const float* W2  = (const float*)d_in[12];
  const float* b2  = (const float*)d_in[13];
  const float* W3  = (const float*)d_in[14];
  const float* b3  = (const float*)d_in[15];
  const float* g0  = (const float*)d_in[16];
  const float* be0 = (const float*)d_in[17];
  const float* g1  = (const float*)d_in[18];
  const float* be1 = (const float*)d_in[19];
  const float* g2  = (const float*)d_in[20];
  const float* be2 = (const float*)d_in[21];

  // ws: W0b @0 (1,179,648 B) | W1b @1,179,648 (2,097,152) | W2b @3,276,800
  // (1,048,576). Total 4,325,376 B.
  char* ws = (char*)d_ws;
  unsigned short* W0b = (unsigned short*)(ws);
  unsigned short* W1b = (unsigned short*)(ws + 1179648LL);
  unsigned short* W2b = (unsigned short*)(ws + 3276800LL);

  convert_f2bf<<<dim3((147456 + 255) / 256), dim3(256), 0, stream>>>(
      W0, W0b, 147456);
  convert_f2bf<<<dim3((262144 + 255) / 256), dim3(256), 0, stream>>>(
      W1, W1b, 262144);
  convert_f2bf<<<dim3((131072 + 255) / 256), dim3(256), 0, stream>>>(
      W2, W2b, 131072);
  fused_mlp<<<dim3(1024), dim3(512), 0, stream>>>(
      x, kc_emb, nl_emb, op_w, op_b, ic_emb, is_emb, ii_emb,
      W0b, b0, g0, be0, W1b, b1, g1, be1, W2b, b2, g2, be2,
      W3, b3, (float*)d_out);
}